// Round 17
// baseline (166.705 us; speedup 1.0000x reference)
//
#include <hip/hip_runtime.h>
#include <math.h>

// VP-SDE Euler-Maruyama forward diffusion (fp32).
// out[0] = x; out[t+1] = a_t * out[t] + b_t * noise[t],  t = 0..99
//
// Ladder: R4 178.5 | R9 177.8 | cached/LDS/prod-cons 183-192 | R12 164.2
// (chunk-major 2KB/wave/plane) | R13/R14 fattening: dead | R15 cached: flat
// (NOT HBM-BW-bound) | R16 161.8 (XCD swizzle: contiguous 512KB/XCD).
// Locality consolidation pays at every granularity (wave, XCD). R17 tests
// the last one: TIME. Barrier-free waves drift across the 100-plane sweep;
// 4 waves/block at different plane offsets = 4 fragmented streams per CU.
// Raw s_barrier per 4-plane cycle (NOT __syncthreads -- that drains vmcnt
// and would kill the prefetch pipeline) bounds skew to <=1 cycle.

#define S_STEPS 100
#define DEPTH 4                 // pipeline depth in planes

typedef float f32x4 __attribute__((ext_vector_type(4)));

__global__ __launch_bounds__(256) void vpsde_fwd_kernel(
    const f32x4* __restrict__ x,
    const f32x4* __restrict__ noise,
    f32x4* __restrict__ out,
    int ne4)  // float4 per plane (262,144)
{
    __shared__ float s_a[S_STEPS];
    __shared__ float s_b[S_STEPS];

    const int tid = threadIdx.x;
    if (tid < S_STEPS) {
        const float dt = 0.01f;
        float nt_ = (float)tid * dt;           // (t-1)/S for t=1..S
        float beta = 0.1f + nt_ * 19.9f;
        s_a[tid] = 1.0f - 0.5f * beta * dt;
        s_b[tid] = sqrtf(beta) * 0.1f;         // sqrt(beta)*sqrt(dt)
    }
    __syncthreads();

    const int wid  = tid >> 6;
    const int lane = tid & 63;

    // XCD-aware swizzle: XCD (bid&7) owns contiguous data tiles.
    const int bid   = blockIdx.x;
    const int dtile = ((bid & 7) << 6) | (bid >> 3);   // bijective for 512

    // Chunk-major: wave covers 128 consecutive float4 (2KB) per plane.
    const size_t base = (size_t)dtile * 512 + (size_t)wid * 128 + lane;

    const f32x4* gl = noise + base;        // running load ptr (plane t)
    f32x4*       st = out + base + ne4;    // running store ptr (plane t+1)

    f32x4 xv0 = x[base];
    f32x4 xv1 = x[base + 64];
    __builtin_nontemporal_store(xv0, out + base);        // out[0] = x
    __builtin_nontemporal_store(xv1, out + base + 64);

    int t = 0;                              // current plane index

    f32x4 A[2], B[2], C[2], Dq[2];

    auto loadp = [&](f32x4* buf) {          // one plane: 2 contiguous loads
        buf[0] = __builtin_nontemporal_load(gl);
        buf[1] = __builtin_nontemporal_load(gl + 64);
        gl += ne4;
    };
    auto consume = [&](const f32x4* buf) {  // fma + 2 contiguous stores
        const float a = s_a[t];
        const float b = s_b[t];
        xv0 = a * xv0 + b * buf[0];
        xv1 = a * xv1 + b * buf[1];
        __builtin_nontemporal_store(xv0, st);
        __builtin_nontemporal_store(xv1, st + 64);
        st += ne4;
        ++t;
    };

    // Prologue: 4 planes in flight (8 loads, 8KB/wave).
    loadp(A); loadp(B); loadp(C); loadp(Dq);

    // 24 cycles x 4 planes; raw barrier keeps the block's 4 waves in
    // lockstep (bounds plane-offset skew) WITHOUT draining vmcnt.
    #pragma unroll 1
    for (int cyc = 0; cyc < (S_STEPS / DEPTH) - 1; ++cyc) {
        consume(A);  loadp(A);
        consume(B);  loadp(B);
        consume(C);  loadp(C);
        consume(Dq); loadp(Dq);
        __builtin_amdgcn_s_barrier();       // time-alignment only
    }
    // Epilogue: planes 96..99.
    consume(A); consume(B); consume(C); consume(Dq);
}

extern "C" void kernel_launch(void* const* d_in, const int* in_sizes, int n_in,
                              void* d_out, int out_size, void* d_ws, size_t ws_size,
                              hipStream_t stream) {
    const float* x     = (const float*)d_in[0];   // (64,256,64)
    const float* noise = (const float*)d_in[1];   // (100,64,256,64)
    float* out         = (float*)d_out;           // (101,64,256,64)

    const int ne  = in_sizes[0];       // 1,048,576 floats per plane
    const int ne4 = ne / 4;            // 262,144 float4 per plane

    const int block = 256;
    const int grid  = ne4 / 512;       // 512 blocks (block tile = 8KB/plane)

    vpsde_fwd_kernel<<<grid, block, 0, stream>>>(
        (const f32x4*)x, (const f32x4*)noise, (f32x4*)out, ne4);
}

// Round 18
// 163.327 us; speedup vs baseline: 1.0207x; 1.0207x over previous
//
#include <hip/hip_runtime.h>
#include <math.h>

// VP-SDE Euler-Maruyama forward diffusion (fp32).
// out[0] = x; out[t+1] = a_t * out[t] + b_t * noise[t],  t = 0..99
//
// Ladder: R4 178.5 | R9 177.8 | cached/LDS/prod-cons 183-192 | R12 164.2
// (chunk-major 2KB/wave/plane) | R13/R14 fattening: dead | R15 cached: flat
// (not HBM-BW-bound) | R16 161.8 (XCD swizzle) | R17 166.7 (barrier: dead).
// R18: last locality lever -- pipeline DEPTH. DEPTH=4 keeps each wave's
// outstanding ops spread over ~8 plane-regions (4 load + 4 store planes);
// DEPTH=2 halves that to 4 while retaining 4KB/wave in flight (32KB/CU,
// ~2.7x the latency-hiding requirement). Single-variable change vs R16.

#define S_STEPS 100

typedef float f32x4 __attribute__((ext_vector_type(4)));

__global__ __launch_bounds__(256) void vpsde_fwd_kernel(
    const f32x4* __restrict__ x,
    const f32x4* __restrict__ noise,
    f32x4* __restrict__ out,
    int ne4)  // float4 per plane (262,144)
{
    __shared__ float s_a[S_STEPS];
    __shared__ float s_b[S_STEPS];

    const int tid = threadIdx.x;
    if (tid < S_STEPS) {
        const float dt = 0.01f;
        float nt_ = (float)tid * dt;           // (t-1)/S for t=1..S
        float beta = 0.1f + nt_ * 19.9f;
        s_a[tid] = 1.0f - 0.5f * beta * dt;
        s_b[tid] = sqrtf(beta) * 0.1f;         // sqrt(beta)*sqrt(dt)
    }
    __syncthreads();

    const int wid  = tid >> 6;
    const int lane = tid & 63;

    // XCD-aware swizzle: XCD (bid&7) owns contiguous data tiles.
    const int bid   = blockIdx.x;
    const int dtile = ((bid & 7) << 6) | (bid >> 3);   // bijective for 512

    // Chunk-major: wave covers 128 consecutive float4 (2KB) per plane.
    const size_t base = (size_t)dtile * 512 + (size_t)wid * 128 + lane;

    const f32x4* gl = noise + base;        // running load ptr (plane t)
    f32x4*       st = out + base + ne4;    // running store ptr (plane t+1)

    f32x4 xv0 = x[base];
    f32x4 xv1 = x[base + 64];
    __builtin_nontemporal_store(xv0, out + base);        // out[0] = x
    __builtin_nontemporal_store(xv1, out + base + 64);

    int t = 0;                              // current plane index

    f32x4 A[2], B[2];

    auto loadp = [&](f32x4* buf) {          // one plane: 2 contiguous loads
        buf[0] = __builtin_nontemporal_load(gl);
        buf[1] = __builtin_nontemporal_load(gl + 64);
        gl += ne4;
    };
    auto consume = [&](const f32x4* buf) {  // fma + 2 contiguous stores
        const float a = s_a[t];
        const float b = s_b[t];
        xv0 = a * xv0 + b * buf[0];
        xv1 = a * xv1 + b * buf[1];
        __builtin_nontemporal_store(xv0, st);
        __builtin_nontemporal_store(xv1, st + 64);
        st += ne4;
        ++t;
    };

    // Prologue: 2 planes in flight (4 loads, 4KB/wave).
    loadp(A); loadp(B);

    // 49 cycles x 2 planes = 98 consumed; planes 2..99 loaded on the fly.
    #pragma unroll 1
    for (int cyc = 0; cyc < (S_STEPS / 2) - 1; ++cyc) {
        consume(A);  loadp(A);
        consume(B);  loadp(B);
    }
    // Epilogue: planes 98..99.
    consume(A); consume(B);
}

extern "C" void kernel_launch(void* const* d_in, const int* in_sizes, int n_in,
                              void* d_out, int out_size, void* d_ws, size_t ws_size,
                              hipStream_t stream) {
    const float* x     = (const float*)d_in[0];   // (64,256,64)
    const float* noise = (const float*)d_in[1];   // (100,64,256,64)
    float* out         = (float*)d_out;           // (101,64,256,64)

    const int ne  = in_sizes[0];       // 1,048,576 floats per plane
    const int ne4 = ne / 4;            // 262,144 float4 per plane

    const int block = 256;
    const int grid  = ne4 / 512;       // 512 blocks (block tile = 8KB/plane)

    vpsde_fwd_kernel<<<grid, block, 0, stream>>>(
        (const f32x4*)x, (const f32x4*)noise, (f32x4*)out, ne4);
}